// Round 6
// baseline (213.772 us; speedup 1.0000x reference)
//
#include <hip/hip_runtime.h>
#include <hip/hip_bf16.h>
#include <stdint.h>
#include <stddef.h>

#define DIM 1024
#define SEQ 2048
#define KF 24

using f32x4  = __attribute__((ext_vector_type(4))) float;
using bf16x8 = __attribute__((ext_vector_type(8))) short;

__device__ __forceinline__ unsigned short f2bf(float f){
  union { float f; unsigned int i; } v; v.f = f;
  unsigned int r = v.i + 0x7FFFu + ((v.i >> 16) & 1u);  // RNE
  return (unsigned short)(r >> 16);
}
// D = a.bf16[0]*b.bf16[0] + a.bf16[1]*b.bf16[1] + c   (V_DOT2_F32_BF16, VOP3P)
__device__ __forceinline__ float dot2bf(unsigned int a, unsigned int b, float c){
  float d;
  asm("v_dot2_f32_bf16 %0, %1, %2, %3" : "=v"(d) : "v"(a), "v"(b), "v"(c));
  return d;
}
__device__ __forceinline__ void gload_lds16(const void* g, void* l){
  __builtin_amdgcn_global_load_lds(
      (const __attribute__((address_space(1))) unsigned int*)g,
      (__attribute__((address_space(3))) unsigned int*)l, 16, 0, 0);
}
__device__ __forceinline__ void gload_lds4(const void* g, void* l){
  __builtin_amdgcn_global_load_lds(
      (const __attribute__((address_space(1))) unsigned int*)g,
      (__attribute__((address_space(3))) unsigned int*)l, 4, 0, 0);
}

// ---------------- prep: x fp32 -> bf16 ----------------
__global__ void k_cvt_x(const float* __restrict__ x, unsigned short* __restrict__ xb){
  int i = blockIdx.x * 256 + threadIdx.x;            // each thread 4 elems
  const float4* x4 = (const float4*)x;
  float4 v = x4[i];
  ushort4 o;
  o.x = f2bf(v.x); o.y = f2bf(v.y); o.z = f2bf(v.z); o.w = f2bf(v.w);
  *(ushort4*)(xb + (size_t)i * 4) = o;
}

// ---------------- prep: M_inputs transpose -> bf16 (B^T, [d][e]) ----------------
__global__ void k_tr_M(const float* __restrict__ Mi, unsigned short* __restrict__ MbT){
  __shared__ float tile[32][33];
  int e0 = blockIdx.y * 32, d0 = blockIdx.x * 32;
  int tx = threadIdx.x, ty = threadIdx.y;            // block (32,8)
  #pragma unroll
  for (int r = 0; r < 32; r += 8)
    tile[ty + r][tx] = Mi[(size_t)(e0 + ty + r) * DIM + d0 + tx];
  __syncthreads();
  #pragma unroll
  for (int r = 0; r < 32; r += 8)
    MbT[(size_t)(d0 + ty + r) * DIM + e0 + tx] = f2bf(tile[tx][ty + r]);
}

// ---------------- prep: pe packed pairs, TRANSPOSED [d][512] ----------------
// pepkT[d][r2] = u32{ lo = 2*phi[4*r2][d], hi = 2*phi[4*r2+2][d] }
__global__ void k_pe(const float* __restrict__ filters, const float* __restrict__ Mf,
                     unsigned int* __restrict__ pepkT){
  int r2 = blockIdx.x * 256 + threadIdx.x;           // 0..511 (grid.x = 2)
  int d  = blockIdx.y;                               // 0..1023
  float a0 = 0.f, a1 = 0.f;
  #pragma unroll
  for (int k = 0; k < KF; ++k){
    float mf = Mf[(size_t)k * DIM + d];              // uniform per block
    a0 += filters[(size_t)(4 * r2)     * KF + k] * mf;
    a1 += filters[(size_t)(4 * r2 + 2) * KF + k] * mf;
  }
  unsigned int lo = f2bf(2.f * a0), hi = f2bf(2.f * a1);
  pepkT[(size_t)d * 512 + r2] = lo | (hi << 16);
}

// ---------------- GEMM: x_proj = x @ M_inputs, epilogue writes BIGRAM ----------------
// Bg[bt][d] (u32) = y[bt][d] | y[bt-2][d]<<16  (bt-2 within same batch, else 0).
#define BM 128
#define BN 128
#define BKK 64
__global__ void k_gemm(const unsigned short* __restrict__ A,
                       const unsigned short* __restrict__ Bt,
                       unsigned int* __restrict__ Bg){
  __shared__ unsigned short As[BM * BKK];   // 16 KB, XOR-swizzled (unit16B ^= row&7)
  __shared__ unsigned short Bs[BN * BKK];   // 16 KB
  int tid  = threadIdx.x;
  int lane = tid & 63, wave = tid >> 6;
  int wm = wave >> 1, wn = wave & 1;
  int trow0 = blockIdx.x * BM;
  int ncol0 = blockIdx.y * BN;

  f32x4 acc[4][4] = {};

  for (int kt = 0; kt < 1024 / BKK; ++kt){
    __syncthreads();
    #pragma unroll
    for (int g = 0; g < 4; ++g){
      int c  = wave * 4 + g;              // chunk 0..15, 1KB each
      int mr = c * 8 + (lane >> 3);       // tile row this lane stages
      int u  = lane & 7;                  // physical 16B unit within row
      int su = u ^ (mr & 7);              // source (logical) unit
      const unsigned short* srcA = A + (size_t)(trow0 + mr) * 1024 + kt * BKK + su * 8;
      gload_lds16(srcA, (char*)As + c * 1024);
      const unsigned short* srcB = Bt + (size_t)(ncol0 + mr) * 1024 + kt * BKK + su * 8;
      gload_lds16(srcB, (char*)Bs + c * 1024);
    }
    __syncthreads();

    bf16x8 af[4][2], bfr[4][2];
    #pragma unroll
    for (int mi = 0; mi < 4; ++mi){
      int row = wm * 64 + mi * 16 + (lane & 15);
      #pragma unroll
      for (int ks = 0; ks < 2; ++ks){
        int u = ((lane >> 4) + 4 * ks) ^ (row & 7);
        af[mi][ks] = *(const bf16x8*)((const char*)As + row * 128 + u * 16);
      }
    }
    #pragma unroll
    for (int ni = 0; ni < 4; ++ni){
      int row = wn * 64 + ni * 16 + (lane & 15);
      #pragma unroll
      for (int ks = 0; ks < 2; ++ks){
        int u = ((lane >> 4) + 4 * ks) ^ (row & 7);
        bfr[ni][ks] = *(const bf16x8*)((const char*)Bs + row * 128 + u * 16);
      }
    }
    #pragma unroll
    for (int mi = 0; mi < 4; ++mi)
      #pragma unroll
      for (int ni = 0; ni < 4; ++ni)
        #pragma unroll
        for (int ks = 0; ks < 2; ++ks)
          acc[mi][ni] = __builtin_amdgcn_mfma_f32_16x16x32_bf16(
              af[mi][ks], bfr[ni][ks], acc[mi][ni], 0, 0, 0);
  }

  unsigned short* Bh = (unsigned short*)Bg;
  #pragma unroll
  for (int mi = 0; mi < 4; ++mi)
    #pragma unroll
    for (int ni = 0; ni < 4; ++ni){
      int col = ncol0 + wn * 64 + ni * 16 + (lane & 15);
      #pragma unroll
      for (int reg = 0; reg < 4; ++reg){
        int row = trow0 + wm * 64 + mi * 16 + (lane >> 4) * 4 + reg;
        unsigned short y = f2bf(acc[mi][ni][reg]);
        int t = row & 2047;
        size_t idx = (size_t)row * 1024 + col;
        if (t < 2) Bg[idx] = (unsigned int)y;          // lo=y, hi=0 (no y[t-2])
        else       Bh[2 * idx] = y;                    // lo half
        if (t < 2046)
          Bh[2 * ((size_t)(row + 2) * 1024 + col) + 1] = y;  // hi half of bt+2
      }
    }
}

// ---------------- depthwise causal conv: 2-phase LDS pipeline + dot2 ----------------
// out[m0+m] = sum_{r<=m0+m} pe[r]*y[m0+m-r] per (b,p,d) column.
// Chunk c: taps r0 = m0-16c .. +15. acc[m] += dot2(pv[q], W[m+14-2q]),
// W[s] = Bg_col[16c-14+s]. Fresh 16 rows (s=14..29) staged via global_load_lds
// double-buffer (issued one chunk ahead — cannot be sunk by the compiler);
// s=0..13 slides in registers. One __syncthreads (vmcnt drain) per chunk.
#define MV 16
__device__ __forceinline__ void dot_block(uint4 a, uint4 b,
                                          const unsigned int* __restrict__ W,
                                          float* __restrict__ acc){
  const unsigned int pq[8] = {a.x, a.y, a.z, a.w, b.x, b.y, b.z, b.w};
  #pragma unroll
  for (int q = 0; q < 8; ++q)
    #pragma unroll
    for (int m = 0; m < MV; ++m)
      acc[m] = dot2bf(pq[q], W[m + 14 - 2 * q], acc[m]);
}

__global__ __launch_bounds__(256, 4)
void k_conv(const unsigned int* __restrict__ Bg,     // [8192][1024] bigram pairs
            const unsigned int* __restrict__ pepkT,  // [1024][512] packed pe pairs
            float* __restrict__ out){                // [4][2048][1024] f32
  __shared__ unsigned int tile[2][16][256];          // 32 KB double buffer
  int tid  = threadIdx.x;
  int wave = tid >> 6;
  int d  = blockIdx.x * 256 + tid;          // 0..1023
  int mt = 63 - blockIdx.y;                 // longest-first (LPT)
  int bp = blockIdx.z;                      // 0..7
  int b = bp >> 1, p = bp & 1;
  const unsigned int* bcol = Bg + ((size_t)(b * SEQ + p) * 1024 + d);  // + j*2048
  const unsigned int* pcol = pepkT + (size_t)d * 512;
  int m0 = mt * MV;

  float acc[MV];
  #pragma unroll
  for (int m = 0; m < MV; ++m) acc[m] = 0.f;

  unsigned int W[30];
  #pragma unroll
  for (int s = 0; s < 14; ++s) W[s] = 0u;   // j<0 zeros for chunk 0

  // prologue: stage chunk 0 (rows 0..15) into buf 0; load pe for chunk 0
  #pragma unroll
  for (int t = 0; t < 16; ++t)
    gload_lds4(bcol + (size_t)t * 2048, &tile[0][t][wave * 64]);
  uint4 pva = *(const uint4*)(pcol + 8 * mt);
  uint4 pvb = *(const uint4*)(pcol + 8 * mt + 4);
  __syncthreads();   // vmcnt(0) drain: chunk-0 data + pe in place

  for (int c = 0; c < mt; ++c){
    int cb = c & 1, nb = cb ^ 1;
    // stage chunk c+1 (rows 16c+16 .. 16c+31) into the other buffer
    #pragma unroll
    for (int t = 0; t < 16; ++t)
      gload_lds4(bcol + (size_t)(16 * (c + 1) + t) * 2048, &tile[nb][t][wave * 64]);
    // next-chunk pe (in flight during compute; drained by the barrier)
    int nr2 = 8 * mt - 8 * (c + 1);
    uint4 npa = *(const uint4*)(pcol + nr2);
    uint4 npb = *(const uint4*)(pcol + nr2 + 4);

    // compute chunk c from buf cb
    #pragma unroll
    for (int t = 0; t < 16; ++t) W[14 + t] = tile[cb][t][tid];
    dot_block(pva, pvb, W, acc);
    #pragma unroll
    for (int s = 0; s < 14; ++s) W[s] = W[s + 16];   // slide window

    __syncthreads();   // drains gload_lds (chunk c+1 ready) + npv loads
    pva = npa; pvb = npb;
  }
  // final chunk (r0 == 0)
  #pragma unroll
  for (int t = 0; t < 16; ++t) W[14 + t] = tile[mt & 1][t][tid];
  dot_block(pva, pvb, W, acc);

  float* ocol = out + ((size_t)(b * SEQ + p) * 1024 + d);
  #pragma unroll
  for (int m = 0; m < MV; ++m)
    ocol[(size_t)(m0 + m) * 2048] = acc[m];
}

extern "C" void kernel_launch(void* const* d_in, const int* in_sizes, int n_in,
                              void* d_out, int out_size, void* d_ws, size_t ws_size,
                              hipStream_t stream){
  const float* x       = (const float*)d_in[0];
  const float* filters = (const float*)d_in[1];
  const float* Mi      = (const float*)d_in[2];
  const float* Mf      = (const float*)d_in[3];

  char* ws = (char*)d_ws;
  unsigned short* Xb    = (unsigned short*)(ws);                              // 16 MB
  unsigned int*   Bg    = (unsigned int*)  (ws + (size_t)16 * 1024 * 1024);   // 32 MB
  unsigned short* MbT   = (unsigned short*)(ws + (size_t)48 * 1024 * 1024);   //  2 MB
  unsigned int*   pepkT = (unsigned int*)  (ws + (size_t)50 * 1024 * 1024);   //  2 MB
  float* out = (float*)d_out;

  hipLaunchKernelGGL(k_cvt_x, dim3(8192), dim3(256), 0, stream, x, Xb);
  hipLaunchKernelGGL(k_tr_M,  dim3(32, 32), dim3(32, 8), 0, stream, Mi, MbT);
  hipLaunchKernelGGL(k_pe,    dim3(2, 1024), dim3(256), 0, stream, filters, Mf, pepkT);
  hipLaunchKernelGGL(k_gemm,  dim3(64, 8), dim3(256), 0, stream, Xb, MbT, Bg);
  hipLaunchKernelGGL(k_conv,  dim3(4, 64, 8), dim3(256), 0, stream, Bg, pepkT, out);
}

// Round 7
// 186.687 us; speedup vs baseline: 1.1451x; 1.1451x over previous
//
#include <hip/hip_runtime.h>
#include <hip/hip_bf16.h>
#include <stdint.h>
#include <stddef.h>

#define DIM 1024
#define SEQ 2048
#define KF 24

using f32x4   = __attribute__((ext_vector_type(4))) float;
using bf16x8  = __attribute__((ext_vector_type(8))) short;
using uint32x4 = __attribute__((ext_vector_type(4))) unsigned int;

__device__ __forceinline__ unsigned short f2bf(float f){
  union { float f; unsigned int i; } v; v.f = f;
  unsigned int r = v.i + 0x7FFFu + ((v.i >> 16) & 1u);  // RNE
  return (unsigned short)(r >> 16);
}
// D = a.bf16[0]*b.bf16[0] + a.bf16[1]*b.bf16[1] + c   (V_DOT2_F32_BF16, VOP3P)
__device__ __forceinline__ float dot2bf(unsigned int a, unsigned int b, float c){
  float d;
  asm("v_dot2_f32_bf16 %0, %1, %2, %3" : "=v"(d) : "v"(a), "v"(b), "v"(c));
  return d;
}
__device__ __forceinline__ void gload_lds16(const void* g, void* l){
  __builtin_amdgcn_global_load_lds(
      (const __attribute__((address_space(1))) unsigned int*)g,
      (__attribute__((address_space(3))) unsigned int*)l, 16, 0, 0);
}
__device__ __forceinline__ uint32x4 make_srsrc(const void* base, unsigned bytes){
  uint32x4 r;
  r.x = (unsigned)(uintptr_t)base;
  r.y = (unsigned)((uintptr_t)base >> 32);   // stride=0
  r.z = bytes;                               // num_records (bytes, stride==0)
  r.w = 0x00020000u;                         // raw untyped dword
  return r;
}

// ---------------- prep: x fp32 -> bf16 ----------------
__global__ void k_cvt_x(const float* __restrict__ x, unsigned short* __restrict__ xb){
  int i = blockIdx.x * 256 + threadIdx.x;            // each thread 4 elems
  const float4* x4 = (const float4*)x;
  float4 v = x4[i];
  ushort4 o;
  o.x = f2bf(v.x); o.y = f2bf(v.y); o.z = f2bf(v.z); o.w = f2bf(v.w);
  *(ushort4*)(xb + (size_t)i * 4) = o;
}

// ---------------- prep: M_inputs transpose -> bf16 (B^T, [d][e]) ----------------
__global__ void k_tr_M(const float* __restrict__ Mi, unsigned short* __restrict__ MbT){
  __shared__ float tile[32][33];
  int e0 = blockIdx.y * 32, d0 = blockIdx.x * 32;
  int tx = threadIdx.x, ty = threadIdx.y;            // block (32,8)
  #pragma unroll
  for (int r = 0; r < 32; r += 8)
    tile[ty + r][tx] = Mi[(size_t)(e0 + ty + r) * DIM + d0 + tx];
  __syncthreads();
  #pragma unroll
  for (int r = 0; r < 32; r += 8)
    MbT[(size_t)(d0 + ty + r) * DIM + e0 + tx] = f2bf(tile[tx][ty + r]);
}

// ---------------- prep: pe packed pairs, TRANSPOSED [d][512] ----------------
// pepkT[d][r2] = u32{ lo = 2*phi[4*r2][d], hi = 2*phi[4*r2+2][d] } = (pe[2r2], pe[2r2+1])
__global__ void k_pe(const float* __restrict__ filters, const float* __restrict__ Mf,
                     unsigned int* __restrict__ pepkT){
  int r2 = blockIdx.x * 256 + threadIdx.x;           // 0..511 (grid.x = 2)
  int d  = blockIdx.y;                               // 0..1023
  float a0 = 0.f, a1 = 0.f;
  #pragma unroll
  for (int k = 0; k < KF; ++k){
    float mf = Mf[(size_t)k * DIM + d];              // uniform per block
    a0 += filters[(size_t)(4 * r2)     * KF + k] * mf;
    a1 += filters[(size_t)(4 * r2 + 2) * KF + k] * mf;
  }
  unsigned int lo = f2bf(2.f * a0), hi = f2bf(2.f * a1);
  pepkT[(size_t)d * 512 + r2] = lo | (hi << 16);
}

// ---------------- GEMM: x_proj = x @ M_inputs, epilogue writes BIGRAM ----------------
// Bg[bt][d] (u32) = y[bt][d] | y[bt-2][d]<<16  (bt-2 within same batch, else 0).
#define BM 128
#define BN 128
#define BKK 64
__global__ void k_gemm(const unsigned short* __restrict__ A,
                       const unsigned short* __restrict__ Bt,
                       unsigned int* __restrict__ Bg){
  __shared__ unsigned short As[BM * BKK];   // 16 KB, XOR-swizzled (unit16B ^= row&7)
  __shared__ unsigned short Bs[BN * BKK];   // 16 KB
  int tid  = threadIdx.x;
  int lane = tid & 63, wave = tid >> 6;
  int wm = wave >> 1, wn = wave & 1;
  int trow0 = blockIdx.x * BM;
  int ncol0 = blockIdx.y * BN;

  f32x4 acc[4][4] = {};

  for (int kt = 0; kt < 1024 / BKK; ++kt){
    __syncthreads();
    #pragma unroll
    for (int g = 0; g < 4; ++g){
      int c  = wave * 4 + g;              // chunk 0..15, 1KB each
      int mr = c * 8 + (lane >> 3);       // tile row this lane stages
      int u  = lane & 7;                  // physical 16B unit within row
      int su = u ^ (mr & 7);              // source (logical) unit
      const unsigned short* srcA = A + (size_t)(trow0 + mr) * 1024 + kt * BKK + su * 8;
      gload_lds16(srcA, (char*)As + c * 1024);
      const unsigned short* srcB = Bt + (size_t)(ncol0 + mr) * 1024 + kt * BKK + su * 8;
      gload_lds16(srcB, (char*)Bs + c * 1024);
    }
    __syncthreads();

    bf16x8 af[4][2], bfr[4][2];
    #pragma unroll
    for (int mi = 0; mi < 4; ++mi){
      int row = wm * 64 + mi * 16 + (lane & 15);
      #pragma unroll
      for (int ks = 0; ks < 2; ++ks){
        int u = ((lane >> 4) + 4 * ks) ^ (row & 7);
        af[mi][ks] = *(const bf16x8*)((const char*)As + row * 128 + u * 16);
      }
    }
    #pragma unroll
    for (int ni = 0; ni < 4; ++ni){
      int row = wn * 64 + ni * 16 + (lane & 15);
      #pragma unroll
      for (int ks = 0; ks < 2; ++ks){
        int u = ((lane >> 4) + 4 * ks) ^ (row & 7);
        bfr[ni][ks] = *(const bf16x8*)((const char*)Bs + row * 128 + u * 16);
      }
    }
    #pragma unroll
    for (int mi = 0; mi < 4; ++mi)
      #pragma unroll
      for (int ni = 0; ni < 4; ++ni)
        #pragma unroll
        for (int ks = 0; ks < 2; ++ks)
          acc[mi][ni] = __builtin_amdgcn_mfma_f32_16x16x32_bf16(
              af[mi][ks], bfr[ni][ks], acc[mi][ni], 0, 0, 0);
  }

  unsigned short* Bh = (unsigned short*)Bg;
  #pragma unroll
  for (int mi = 0; mi < 4; ++mi)
    #pragma unroll
    for (int ni = 0; ni < 4; ++ni){
      int col = ncol0 + wn * 64 + ni * 16 + (lane & 15);
      #pragma unroll
      for (int reg = 0; reg < 4; ++reg){
        int row = trow0 + wm * 64 + mi * 16 + (lane >> 4) * 4 + reg;
        unsigned short y = f2bf(acc[mi][ni][reg]);
        int t = row & 2047;
        size_t idx = (size_t)row * 1024 + col;
        if (t < 2) Bg[idx] = (unsigned int)y;          // lo=y, hi=0 (no y[t-2])
        else       Bh[2 * idx] = y;                    // lo half
        if (t < 2046)
          Bh[2 * ((size_t)(row + 2) * 1024 + col) + 1] = y;  // hi half of bt+2
      }
    }
}

// ---------------- depthwise causal conv: asm buffer_load pipeline + dot2 ----------------
// out[m0+m] = sum_{r<=m0+m} pe[r]*y[m0+m-r] per (b,p,d) column.
// Chunk c (c=0..mt): taps r0 = m0-16c .. +15, window rows j = 16c-14 .. 16c+15.
// Window = Wlo[14] (sliding regs) + cur[16] (fresh rows). Next chunk's 16 rows +
// pe pairs prefetched via VOLATILE asm buffer_loads (order-pinned, zero VALU
// addressing: const VGPR voffsets + SGPR soffset). One s_waitcnt vmcnt(0) +
// sched_barrier per chunk; no LDS, no __syncthreads.
__device__ __forceinline__ void dot_block(uint32x4 a, uint32x4 b,
                                          const unsigned* __restrict__ Wlo,
                                          const unsigned* __restrict__ cur,
                                          float* __restrict__ acc){
  const unsigned pq[8] = {a.x, a.y, a.z, a.w, b.x, b.y, b.z, b.w};
  #pragma unroll
  for (int q = 0; q < 8; ++q)
    #pragma unroll
    for (int m = 0; m < 16; ++m){
      int idx = m + 14 - 2 * q;                     // window index 0..29
      unsigned w = (idx < 14) ? Wlo[idx] : cur[idx - 14];
      acc[m] = dot2bf(pq[q], w, acc[m]);
    }
}

#define BLOADX(dst, vo, so) \
  asm volatile("buffer_load_dword %0, %1, %2, %3 offen" \
               : "=v"(dst) : "v"(vo), "s"(xrsrc), "s"(so))
#define BLOADP0(dst, vo, so) \
  asm volatile("buffer_load_dwordx4 %0, %1, %2, %3 offen" \
               : "=v"(dst) : "v"(vo), "s"(prsrc), "s"(so))
#define BLOADP16(dst, vo, so) \
  asm volatile("buffer_load_dwordx4 %0, %1, %2, %3 offen offset:16" \
               : "=v"(dst) : "v"(vo), "s"(prsrc), "s"(so))

__global__ __launch_bounds__(256, 4)
void k_conv(const unsigned int* __restrict__ Bg,     // [8192][1024] bigram pairs
            const unsigned int* __restrict__ pepkT,  // [1024][512] packed pe pairs
            float* __restrict__ out){                // [4][2048][1024] f32
  int tid = threadIdx.x;
  int d   = blockIdx.x * 256 + tid;         // 0..1023
  int mt  = 63 - blockIdx.y;                // longest-first (LPT)
  int bp  = blockIdx.z;                     // 0..7
  int b = bp >> 1, p = bp & 1;
  int m0 = mt * 16;

  uint32x4 xrsrc = make_srsrc(Bg + (size_t)(b * SEQ + p) * 1024, 1024u * 8192u);
  uint32x4 prsrc = make_srsrc(pepkT, 1024u * 2048u);

  unsigned voff[16];                        // constant per-lane byte offsets
  #pragma unroll
  for (int t = 0; t < 16; ++t) voff[t] = (unsigned)(d * 4 + t * 8192);
  unsigned pvoff = (unsigned)(d * 2048);

  float acc[16];
  #pragma unroll
  for (int m = 0; m < 16; ++m) acc[m] = 0.f;
  unsigned Wlo[14];
  #pragma unroll
  for (int s = 0; s < 14; ++s) Wlo[s] = 0u;  // j<0 zeros for chunk 0

  unsigned cur[16], nxt[16];
  unsigned soff  = 0u;                       // byte offset of row 16c
  unsigned psoff = 32u * (unsigned)mt;       // byte offset of r2 = 8(mt-c)
  uint32x4 pva, pvb, npa, npb;

  // prologue: chunk 0 data + pe
  #pragma unroll
  for (int t = 0; t < 16; ++t) BLOADX(cur[t], voff[t], soff);
  BLOADP0 (pva, pvoff, psoff);
  BLOADP16(pvb, pvoff, psoff);
  asm volatile("s_waitcnt vmcnt(0)" ::: "memory");
  __builtin_amdgcn_sched_barrier(0);

  for (int c = 0; c < mt; ++c){
    soff += 131072u; psoff -= 32u;
    // issue chunk c+1 loads (volatile: cannot sink below compute)
    #pragma unroll
    for (int t = 0; t < 16; ++t) BLOADX(nxt[t], voff[t], soff);
    BLOADP0 (npa, pvoff, psoff);
    BLOADP16(npb, pvoff, psoff);
    __builtin_amdgcn_sched_barrier(0);
    // compute chunk c (latency of the 18 loads hides under 128 dot2)
    dot_block(pva, pvb, Wlo, cur, acc);
    #pragma unroll
    for (int s = 0; s < 14; ++s) Wlo[s] = cur[s + 2];   // slide window
    __builtin_amdgcn_sched_barrier(0);
    asm volatile("s_waitcnt vmcnt(0)" ::: "memory");
    __builtin_amdgcn_sched_barrier(0);
    #pragma unroll
    for (int t = 0; t < 16; ++t) cur[t] = nxt[t];
    pva = npa; pvb = npb;
  }
  dot_block(pva, pvb, Wlo, cur, acc);        // final chunk (r0 == 0)

  float* ocol = out + ((size_t)(b * SEQ + p) * 1024 + d);
  #pragma unroll
  for (int m = 0; m < 16; ++m)
    ocol[(size_t)(m0 + m) * 2048] = acc[m];
}

extern "C" void kernel_launch(void* const* d_in, const int* in_sizes, int n_in,
                              void* d_out, int out_size, void* d_ws, size_t ws_size,
                              hipStream_t stream){
  const float* x       = (const float*)d_in[0];
  const float* filters = (const float*)d_in[1];
  const float* Mi      = (const float*)d_in[2];
  const float* Mf      = (const float*)d_in[3];

  char* ws = (char*)d_ws;
  unsigned short* Xb    = (unsigned short*)(ws);                              // 16 MB
  unsigned int*   Bg    = (unsigned int*)  (ws + (size_t)16 * 1024 * 1024);   // 32 MB
  unsigned short* MbT   = (unsigned short*)(ws + (size_t)48 * 1024 * 1024);   //  2 MB
  unsigned int*   pepkT = (unsigned int*)  (ws + (size_t)50 * 1024 * 1024);   //  2 MB
  float* out = (float*)d_out;

  hipLaunchKernelGGL(k_cvt_x, dim3(8192), dim3(256), 0, stream, x, Xb);
  hipLaunchKernelGGL(k_tr_M,  dim3(32, 32), dim3(32, 8), 0, stream, Mi, MbT);
  hipLaunchKernelGGL(k_pe,    dim3(2, 1024), dim3(256), 0, stream, filters, Mf, pepkT);
  hipLaunchKernelGGL(k_gemm,  dim3(64, 8), dim3(256), 0, stream, Xb, MbT, Bg);
  hipLaunchKernelGGL(k_conv,  dim3(4, 64, 8), dim3(256), 0, stream, Bg, pepkT, out);
}

// Round 8
// 135.507 us; speedup vs baseline: 1.5776x; 1.3777x over previous
//
#include <hip/hip_runtime.h>
#include <hip/hip_bf16.h>
#include <stdint.h>
#include <stddef.h>

#define DIM 1024
#define SEQ 2048
#define KF 24

using f32x4    = __attribute__((ext_vector_type(4))) float;
using bf16x8   = __attribute__((ext_vector_type(8))) short;
using uint32x4 = __attribute__((ext_vector_type(4))) unsigned int;

__device__ __forceinline__ unsigned short f2bf(float f){
  union { float f; unsigned int i; } v; v.f = f;
  unsigned int r = v.i + 0x7FFFu + ((v.i >> 16) & 1u);  // RNE
  return (unsigned short)(r >> 16);
}
// D = a.bf16[0]*b.bf16[0] + a.bf16[1]*b.bf16[1] + c   (V_DOT2_F32_BF16, VOP3P)
__device__ __forceinline__ float dot2bf(unsigned int a, unsigned int b, float c){
  float d;
  asm("v_dot2_f32_bf16 %0, %1, %2, %3" : "=v"(d) : "v"(a), "v"(b), "v"(c));
  return d;
}
__device__ __forceinline__ unsigned vext(const uint32x4 v, int i){
  return i == 0 ? v.x : i == 1 ? v.y : i == 2 ? v.z : v.w;
}
__device__ __forceinline__ void gload_lds16(const void* g, void* l){
  __builtin_amdgcn_global_load_lds(
      (const __attribute__((address_space(1))) unsigned int*)g,
      (__attribute__((address_space(3))) unsigned int*)l, 16, 0, 0);
}
__device__ __forceinline__ uint32x4 make_srsrc(const void* base, unsigned bytes){
  uint32x4 r;
  r.x = (unsigned)(uintptr_t)base;
  r.y = (unsigned)((uintptr_t)base >> 32);   // stride=0
  r.z = bytes;                               // num_records (bytes); OOB loads -> 0
  r.w = 0x00020000u;                         // raw untyped dword
  return r;
}

// ---------------- prep: x fp32 -> bf16 ----------------
__global__ void k_cvt_x(const float* __restrict__ x, unsigned short* __restrict__ xb){
  int i = blockIdx.x * 256 + threadIdx.x;            // each thread 4 elems
  const float4* x4 = (const float4*)x;
  float4 v = x4[i];
  ushort4 o;
  o.x = f2bf(v.x); o.y = f2bf(v.y); o.z = f2bf(v.z); o.w = f2bf(v.w);
  *(ushort4*)(xb + (size_t)i * 4) = o;
}

// ---------------- prep: M_inputs transpose -> bf16 (B^T, [d][e]) ----------------
__global__ void k_tr_M(const float* __restrict__ Mi, unsigned short* __restrict__ MbT){
  __shared__ float tile[32][33];
  int e0 = blockIdx.y * 32, d0 = blockIdx.x * 32;
  int tx = threadIdx.x, ty = threadIdx.y;            // block (32,8)
  #pragma unroll
  for (int r = 0; r < 32; r += 8)
    tile[ty + r][tx] = Mi[(size_t)(e0 + ty + r) * DIM + d0 + tx];
  __syncthreads();
  #pragma unroll
  for (int r = 0; r < 32; r += 8)
    MbT[(size_t)(d0 + ty + r) * DIM + e0 + tx] = f2bf(tile[tx][ty + r]);
}

// ---------------- prep: pe packed pairs, TRANSPOSED [d][512] ----------------
// pepkT[d][r2] = u32{ lo = 2*phi[4*r2][d], hi = 2*phi[4*r2+2][d] } = (pe[2r2], pe[2r2+1])
__global__ void k_pe(const float* __restrict__ filters, const float* __restrict__ Mf,
                     unsigned int* __restrict__ pepkT){
  int r2 = blockIdx.x * 256 + threadIdx.x;           // 0..511 (grid.x = 2)
  int d  = blockIdx.y;                               // 0..1023
  float a0 = 0.f, a1 = 0.f;
  #pragma unroll
  for (int k = 0; k < KF; ++k){
    float mf = Mf[(size_t)k * DIM + d];              // uniform per block
    a0 += filters[(size_t)(4 * r2)     * KF + k] * mf;
    a1 += filters[(size_t)(4 * r2 + 2) * KF + k] * mf;
  }
  unsigned int lo = f2bf(2.f * a0), hi = f2bf(2.f * a1);
  pepkT[(size_t)d * 512 + r2] = lo | (hi << 16);
}

// ---------------- GEMM: x_proj = x @ M_inputs, epilogue writes Bg4 ----------------
// Bg4 elem (b,p,j,d) at u32 index (b*2+p)*1048576 + (j>>2)*4096 + d*4 + (j&3),
// value = y_j | y_{j-1}<<16 (in-stream; y_{-1}=0).  Lane's 4 consecutive j are
// 16B contiguous -> conv loads dwordx4.
#define BM 128
#define BN 128
#define BKK 64
__global__ void k_gemm(const unsigned short* __restrict__ A,
                       const unsigned short* __restrict__ Bt,
                       unsigned int* __restrict__ Bg){
  __shared__ unsigned short As[BM * BKK];   // 16 KB, XOR-swizzled (unit16B ^= row&7)
  __shared__ unsigned short Bs[BN * BKK];   // 16 KB
  int tid  = threadIdx.x;
  int lane = tid & 63, wave = tid >> 6;
  int wm = wave >> 1, wn = wave & 1;
  int trow0 = blockIdx.x * BM;
  int ncol0 = blockIdx.y * BN;

  f32x4 acc[4][4] = {};

  for (int kt = 0; kt < 1024 / BKK; ++kt){
    __syncthreads();
    #pragma unroll
    for (int g = 0; g < 4; ++g){
      int c  = wave * 4 + g;              // chunk 0..15, 1KB each
      int mr = c * 8 + (lane >> 3);       // tile row this lane stages
      int u  = lane & 7;                  // physical 16B unit within row
      int su = u ^ (mr & 7);              // source (logical) unit
      const unsigned short* srcA = A + (size_t)(trow0 + mr) * 1024 + kt * BKK + su * 8;
      gload_lds16(srcA, (char*)As + c * 1024);
      const unsigned short* srcB = Bt + (size_t)(ncol0 + mr) * 1024 + kt * BKK + su * 8;
      gload_lds16(srcB, (char*)Bs + c * 1024);
    }
    __syncthreads();

    bf16x8 af[4][2], bfr[4][2];
    #pragma unroll
    for (int mi = 0; mi < 4; ++mi){
      int row = wm * 64 + mi * 16 + (lane & 15);
      #pragma unroll
      for (int ks = 0; ks < 2; ++ks){
        int u = ((lane >> 4) + 4 * ks) ^ (row & 7);
        af[mi][ks] = *(const bf16x8*)((const char*)As + row * 128 + u * 16);
      }
    }
    #pragma unroll
    for (int ni = 0; ni < 4; ++ni){
      int row = wn * 64 + ni * 16 + (lane & 15);
      #pragma unroll
      for (int ks = 0; ks < 2; ++ks){
        int u = ((lane >> 4) + 4 * ks) ^ (row & 7);
        bfr[ni][ks] = *(const bf16x8*)((const char*)Bs + row * 128 + u * 16);
      }
    }
    #pragma unroll
    for (int mi = 0; mi < 4; ++mi)
      #pragma unroll
      for (int ni = 0; ni < 4; ++ni)
        #pragma unroll
        for (int ks = 0; ks < 2; ++ks)
          acc[mi][ni] = __builtin_amdgcn_mfma_f32_16x16x32_bf16(
              af[mi][ks], bfr[ni][ks], acc[mi][ni], 0, 0, 0);
  }

  unsigned short* Bh = (unsigned short*)Bg;
  #pragma unroll
  for (int mi = 0; mi < 4; ++mi)
    #pragma unroll
    for (int ni = 0; ni < 4; ++ni){
      int col = ncol0 + wn * 64 + ni * 16 + (lane & 15);
      #pragma unroll
      for (int reg = 0; reg < 4; ++reg){
        int row = trow0 + wm * 64 + mi * 16 + (lane >> 4) * 4 + reg;
        unsigned short y = f2bf(acc[mi][ni][reg]);
        int t = row & 2047, bq = row >> 11;
        int p = t & 1, j = t >> 1;
        size_t strm = ((size_t)bq * 2 + p) * 1048576;
        size_t e_lo = strm + (size_t)(j >> 2) * 4096 + (size_t)col * 4 + (j & 3);
        if (j == 0) Bg[e_lo] = (unsigned int)y;        // lo=y, hi=y_{-1}=0
        else        Bh[2 * e_lo] = y;                  // lo half
        if (j < 1023){
          int j1 = j + 1;
          size_t e_hi = strm + (size_t)(j1 >> 2) * 4096 + (size_t)col * 4 + (j1 & 3);
          Bh[2 * e_hi + 1] = y;                        // hi half of entry j+1
        }
      }
    }
}

// ---------------- depthwise causal conv: 32-row chunks, phase-split prefetch -------
// out[m0+m] = sum_{r<=m0+m} pe[r]*y[m0+m-r], m in [0,32), per (b,p,d) column.
// Chunk c (c=0..mt): taps r = m0-32c .. +31; pair q: j = 32c+m-2q.
// Phase A (m<2q, 240 dot2): reads prev buf.  Then 8+4 dwordx4 prefetch of chunk
// c+1 into prev (WAR on regs orders it after phase A).  Phase B (m>=2q, 272 dot2)
// reads cur and hides the loads.  vmcnt(0)+sched_barrier per chunk (rule 18).
#define BLX4(dst, vo, so) \
  asm volatile("buffer_load_dwordx4 %0, %1, %2, %3 offen" \
               : "=v"(dst) : "v"(vo), "s"(xrsrc), "s"(so))
#define BLP4_0(dst, so) \
  asm volatile("buffer_load_dwordx4 %0, %1, %2, %3 offen" \
               : "=v"(dst) : "v"(pvoff), "s"(prsrc), "s"(so))
#define BLP4_16(dst, so) \
  asm volatile("buffer_load_dwordx4 %0, %1, %2, %3 offen offset:16" \
               : "=v"(dst) : "v"(pvoff), "s"(prsrc), "s"(so))
#define BLP4_32(dst, so) \
  asm volatile("buffer_load_dwordx4 %0, %1, %2, %3 offen offset:32" \
               : "=v"(dst) : "v"(pvoff), "s"(prsrc), "s"(so))
#define BLP4_48(dst, so) \
  asm volatile("buffer_load_dwordx4 %0, %1, %2, %3 offen offset:48" \
               : "=v"(dst) : "v"(pvoff), "s"(prsrc), "s"(so))

#define CHUNK_BODY(CUR, PRV, SKIPA, NSOFF, NPSOFF) do{                           \
  if (!(SKIPA)){                                                                 \
    _Pragma("unroll") for (int q = 0; q < 16; ++q)                               \
      _Pragma("unroll") for (int m = 0; m < 32; ++m)                             \
        if (m < 2 * q)                                                           \
          acc[m] = dot2bf(vext(pv[q >> 2], q & 3),                               \
                          vext(PRV[(m - 2*q + 32) >> 2], (m - 2*q + 32) & 3),    \
                          acc[m]);                                               \
  }                                                                              \
  { unsigned _ns = (NSOFF), _nps = (NPSOFF);                                     \
    _Pragma("unroll") for (int k = 0; k < 8; ++k) BLX4(PRV[k], voff[k], _ns);    \
    BLP4_0 (npv[0], _nps); BLP4_16(npv[1], _nps);                                \
    BLP4_32(npv[2], _nps); BLP4_48(npv[3], _nps); }                              \
  __builtin_amdgcn_sched_barrier(0);                                             \
  _Pragma("unroll") for (int q = 0; q < 16; ++q)                                 \
    _Pragma("unroll") for (int m = 0; m < 32; ++m)                               \
      if (m >= 2 * q)                                                            \
        acc[m] = dot2bf(vext(pv[q >> 2], q & 3),                                 \
                        vext(CUR[(m - 2*q) >> 2], (m - 2*q) & 3), acc[m]);       \
  asm volatile("s_waitcnt vmcnt(0)" ::: "memory");                               \
  __builtin_amdgcn_sched_barrier(0);                                             \
  _Pragma("unroll") for (int k = 0; k < 4; ++k) pv[k] = npv[k];                  \
}while(0)

__global__ __launch_bounds__(256, 2)
void k_conv(const unsigned int* __restrict__ Bg,     // Bg4 interleaved (see k_gemm)
            const unsigned int* __restrict__ pepkT,  // [1024][512] packed pe pairs
            float* __restrict__ out){                // [4][2048][1024] f32
  int tid = threadIdx.x;
  int d   = blockIdx.x * 256 + tid;         // 0..1023
  int pi  = blockIdx.y;                     // pair 0..15 -> tiles {pi, 31-pi}
  int bp  = blockIdx.z;                     // 0..7
  int b = bp >> 1, p = bp & 1;

  uint32x4 xrsrc = make_srsrc(Bg + (size_t)bp * 1048576, 4194304u);  // 4MB stream
  uint32x4 prsrc = make_srsrc(pepkT, 2097152u);

  unsigned voff[8];
  #pragma unroll
  for (int k = 0; k < 8; ++k) voff[k] = (unsigned)(d * 16 + k * 16384);
  unsigned pvoff = (unsigned)(d * 2048);

  float* outb = out + ((size_t)(b * SEQ + p) * 1024 + d);   // + (m0+m)*2048

  uint32x4 b0[8], b1[8], pv[4], npv[4];
  float acc[32];

  #pragma unroll
  for (int ti = 0; ti < 2; ++ti){
    int mt = ti ? (31 - pi) : pi;           // tile index, m0 = 32*mt
    unsigned pbase = 64u * (unsigned)mt;    // pe byte soffset of chunk 0
    int nch = mt + 1;

    #pragma unroll
    for (int m = 0; m < 32; ++m) acc[m] = 0.f;

    // prologue: chunk 0 x rows (quads 0..7) + pe
    #pragma unroll
    for (int k = 0; k < 8; ++k) BLX4(b0[k], voff[k], 0u);
    BLP4_0 (pv[0], pbase); BLP4_16(pv[1], pbase);
    BLP4_32(pv[2], pbase); BLP4_48(pv[3], pbase);
    asm volatile("s_waitcnt vmcnt(0)" ::: "memory");
    __builtin_amdgcn_sched_barrier(0);

    // chunk 0: phase A skipped (j<0 -> zero); bigram hi at j=0 is 0 natively
    CHUNK_BODY(b0, b1, true, 131072u, pbase - 64u);
    for (int c = 1; c < nch; c += 2){
      CHUNK_BODY(b1, b0, false, (unsigned)(c + 1) * 131072u,
                 pbase - 64u * (unsigned)(c + 1));
      if (c + 1 < nch)
        CHUNK_BODY(b0, b1, false, (unsigned)(c + 2) * 131072u,
                   pbase - 64u * (unsigned)(c + 2));
    }

    float* oc = outb + (size_t)mt * 32 * 2048;
    #pragma unroll
    for (int m = 0; m < 32; ++m) oc[(size_t)m * 2048] = acc[m];
  }
}

extern "C" void kernel_launch(void* const* d_in, const int* in_sizes, int n_in,
                              void* d_out, int out_size, void* d_ws, size_t ws_size,
                              hipStream_t stream){
  const float* x       = (const float*)d_in[0];
  const float* filters = (const float*)d_in[1];
  const float* Mi      = (const float*)d_in[2];
  const float* Mf      = (const float*)d_in[3];

  char* ws = (char*)d_ws;
  unsigned short* Xb    = (unsigned short*)(ws);                              // 16 MB
  unsigned int*   Bg    = (unsigned int*)  (ws + (size_t)16 * 1024 * 1024);   // 32 MB
  unsigned short* MbT   = (unsigned short*)(ws + (size_t)48 * 1024 * 1024);   //  2 MB
  unsigned int*   pepkT = (unsigned int*)  (ws + (size_t)50 * 1024 * 1024);   //  2 MB
  float* out = (float*)d_out;

  hipLaunchKernelGGL(k_cvt_x, dim3(8192), dim3(256), 0, stream, x, Xb);
  hipLaunchKernelGGL(k_tr_M,  dim3(32, 32), dim3(32, 8), 0, stream, Mi, MbT);
  hipLaunchKernelGGL(k_pe,    dim3(2, 1024), dim3(256), 0, stream, filters, Mf, pepkT);
  hipLaunchKernelGGL(k_gemm,  dim3(64, 8), dim3(256), 0, stream, Xb, MbT, Bg);
  hipLaunchKernelGGL(k_conv,  dim3(4, 16, 8), dim3(256), 0, stream, Bg, pepkT, out);
}